// Round 3
// baseline (172.011 us; speedup 1.0000x reference)
//
#include <hip/hip_runtime.h>

typedef short v8s __attribute__((ext_vector_type(8)));
typedef float v4f __attribute__((ext_vector_type(4)));

#define Wh   1024
#define Hh   512
#define HWh  (Wh * Hh)
#define Wlr  512
#define HWlr (Wlr * 256)
#define PAD  136          // act row stride in shorts (272 B, 16B-aligned)
#define ITERS 8
#define NBLK  256         // 256 blocks x 16 waves x 8 iters x 16 px = 524288 px

// LDS: wfrag[48*512] shorts (W0:32 frags, W1:16 frags, lane-contiguous 16B frags)
//      actS[16][16*PAD] per-wave activation buffers
#define WFRAG_SHORTS (48 * 512)
#define ACT_SHORTS   (16 * PAD)
#define LDS_BYTES    ((WFRAG_SHORTS + 16 * ACT_SHORTS) * 2)   // 49152+69632 B = 118784

__device__ __forceinline__ unsigned short f2bf(float f) {
    union { float f; unsigned u; } v; v.f = f;
    unsigned r = v.u + 0x7FFFu + ((v.u >> 16) & 1u);  // RNE
    return (unsigned short)(r >> 16);
}

#if __has_builtin(__builtin_amdgcn_cvt_pk_bf16_f32)
typedef __bf16 v2bf __attribute__((ext_vector_type(2)));
__device__ __forceinline__ unsigned pk2(float a, float b) {
    union { v2bf v; unsigned u; } c;
    c.v = __builtin_amdgcn_cvt_pk_bf16_f32(a, b);
    return c.u;
}
#else
__device__ __forceinline__ unsigned pk2(float a, float b) {
    return (unsigned)f2bf(a) | ((unsigned)f2bf(b) << 16);
}
#endif

__device__ __forceinline__ float leaky(float x) { return fmaxf(x, 0.01f * x); }

__global__ __launch_bounds__(1024, 4)
void cmfsm_kernel(const float* __restrict__ lr, const float* __restrict__ hr,
                  const float* __restrict__ w0g, const float* __restrict__ w1g,
                  const float* __restrict__ w2g, const float* __restrict__ w3g,
                  const float* __restrict__ w4g, const float* __restrict__ w5g,
                  const float* __restrict__ t0g, const float* __restrict__ t1g,
                  const float* __restrict__ t2g, const float* __restrict__ fwg,
                  float* __restrict__ out)
{
    extern __shared__ unsigned short smem[];
    unsigned short* wfrag = smem;                    // 48*512 shorts
    unsigned short* actS  = smem + WFRAG_SHORTS;

    const int tid  = threadIdx.x;
    const int lane = tid & 63;
    const int wv   = tid >> 6;
    const int p    = lane & 15;   // MFMA n (pixel)
    const int q    = lane >> 4;   // MFMA k-quad

    // ---- stage W0 (frags 0..31) and W1 (frags 32..47) as lane-contiguous A-frags ----
    for (int e = tid; e < 32 * 64; e += 1024) {
        int f = e >> 6, l = e & 63;
        int mt = f >> 2, ks = f & 3, pp = l & 15, qq = l >> 4;
        const float* src = w0g + (mt * 16 + pp) * 128 + ks * 32 + qq * 8;
        unsigned short* dst = wfrag + f * 512 + l * 8;
#pragma unroll
        for (int j = 0; j < 8; ++j) dst[j] = f2bf(src[j]);
    }
    if (tid < 16 * 64) {
        int f = tid >> 6, l = tid & 63;
        int mt = f >> 2, ks = f & 3, pp = l & 15, qq = l >> 4;
        const float* src = w1g + (mt * 16 + pp) * 128 + ks * 32 + qq * 8;
        unsigned short* dst = wfrag + (32 + f) * 512 + l * 8;
#pragma unroll
        for (int j = 0; j < 8; ++j) dst[j] = f2bf(src[j]);
    }

    // ---- W2 (2x2 frags) and W3 (1 frag) held in VGPRs ----
    v8s w2f[2][2];
#pragma unroll
    for (int mt = 0; mt < 2; ++mt)
#pragma unroll
        for (int ks = 0; ks < 2; ++ks) {
            const float* src = w2g + (mt * 16 + p) * 64 + ks * 32 + q * 8;
            v8s f;
#pragma unroll
            for (int j = 0; j < 8; ++j) f[j] = (short)f2bf(src[j]);
            w2f[mt][ks] = f;
        }
    v8s w3f;
    {
        const float* src = w3g + p * 32 + q * 8;
#pragma unroll
        for (int j = 0; j < 8; ++j) w3f[j] = (short)f2bf(src[j]);
    }

    // ---- fused layers 4+5: w45[r] = sum_j w5[j]*w4[j][4q+r] ----
    float w45[4];
#pragma unroll
    for (int r = 0; r < 4; ++r) {
        float s = 0.f;
#pragma unroll
        for (int j = 0; j < 8; ++j) s += w5g[j] * w4g[j * 16 + q * 4 + r];
        w45[r] = s;
    }

    // ---- weights2: 4 parity values ----
    float w2tab[4];
#pragma unroll
    for (int yp = 0; yp < 2; ++yp)
#pragma unroll
        for (int xp = 0; xp < 2; ++xp) {
            float i0 = xp ? 1.f : -1.f;
            float i1 = yp ? 1.f : -1.f;
            float i2 = 1.41421356237309505f;
            float h0[3], h1[2];
            for (int o = 0; o < 3; ++o)
                h0[o] = leaky(t0g[o*3+0]*i0 + t0g[o*3+1]*i1 + t0g[o*3+2]*i2);
            for (int o = 0; o < 2; ++o)
                h1[o] = leaky(t1g[o*3+0]*h0[0] + t1g[o*3+1]*h0[1] + t1g[o*3+2]*h0[2]);
            w2tab[yp*2+xp] = t2g[0]*h1[0] + t2g[1]*h1[1];
        }
    const float fa = fabsf(fwg[0]);
    const float fb = fabsf(fwg[1]);

    // ---- precomputed lane offsets for rep staging (elements) ----
    unsigned hoff[4][2], loff[4][2];
#pragma unroll
    for (int pass = 0; pass < 4; ++pass) {
        const unsigned ch = pass * 8 + q * 2;
        hoff[pass][0] = ch * (unsigned)HWh + (unsigned)p;
        hoff[pass][1] = hoff[pass][0] + HWh;
        loff[pass][0] = ch * (unsigned)HWlr + (unsigned)(p >> 1);
        loff[pass][1] = loff[pass][0] + HWlr;
    }

    __syncthreads();   // wfrag ready

    unsigned short* A  = actS + wv * ACT_SHORTS;
    unsigned short* Ar = A + p * PAD;        // this lane's pixel row
    unsigned*       Ap = (unsigned*)Ar;

    for (int it = 0; it < ITERS; ++it) {
        const int gbase = (blockIdx.x * ITERS + it) * 256 + wv * 16;  // wave-uniform
        const int y     = gbase >> 10;
        const float* hr_it = hr + gbase;
        const float* lr_it = lr + (y >> 1) * Wlr + ((gbase & 1023) >> 1);

        // ---- build rep[p][0..127] in LDS (bf16) ----
#pragma unroll
        for (int pass = 0; pass < 4; ++pass) {
            float h0 = hr_it[hoff[pass][0]];
            float h1 = hr_it[hoff[pass][1]];
            float l0 = lr_it[loff[pass][0]];
            float l1 = lr_it[loff[pass][1]];
            const int ci = pass * 4 + q;     // dword index = ch>>1
            Ap[ci]      = pk2(l0, l1);            // lr_up
            Ap[16 + ci] = pk2(h0, h1);            // hr
            Ap[32 + ci] = pk2(l0 * h0, l1 * h1);  // product
            float d0 = l0 - h0, d1 = l1 - h1;
            Ap[48 + ci] = pk2(d0 * d0, d1 * d1);  // squared diff
        }

        // ---- layer 0: 128 -> 128 ----
        v4f acc0[8];
#pragma unroll
        for (int mt = 0; mt < 8; ++mt) acc0[mt] = (v4f){0.f, 0.f, 0.f, 0.f};
#pragma unroll
        for (int ks = 0; ks < 4; ++ks) {
            v8s b = *(const v8s*)(Ar + ks * 32 + q * 8);
#pragma unroll
            for (int mt = 0; mt < 8; ++mt) {
                v8s a = *(const v8s*)(wfrag + (mt * 4 + ks) * 512 + lane * 8);
                acc0[mt] = __builtin_amdgcn_mfma_f32_16x16x32_bf16(a, b, acc0[mt], 0, 0, 0);
            }
        }
#pragma unroll
        for (int mt = 0; mt < 8; ++mt) {
            uint2 v;
            v.x = pk2(leaky(acc0[mt][0]), leaky(acc0[mt][1]));
            v.y = pk2(leaky(acc0[mt][2]), leaky(acc0[mt][3]));
            *(uint2*)(Ar + mt * 16 + q * 4) = v;   // act[p][16mt+4q+r]
        }

        // ---- layer 1: 128 -> 64 ----
        v4f acc1[4];
#pragma unroll
        for (int mt = 0; mt < 4; ++mt) acc1[mt] = (v4f){0.f, 0.f, 0.f, 0.f};
#pragma unroll
        for (int ks = 0; ks < 4; ++ks) {
            v8s b = *(const v8s*)(Ar + ks * 32 + q * 8);
#pragma unroll
            for (int mt = 0; mt < 4; ++mt) {
                v8s a = *(const v8s*)(wfrag + (32 + mt * 4 + ks) * 512 + lane * 8);
                acc1[mt] = __builtin_amdgcn_mfma_f32_16x16x32_bf16(a, b, acc1[mt], 0, 0, 0);
            }
        }
#pragma unroll
        for (int mt = 0; mt < 4; ++mt) {
            uint2 v;
            v.x = pk2(leaky(acc1[mt][0]), leaky(acc1[mt][1]));
            v.y = pk2(leaky(acc1[mt][2]), leaky(acc1[mt][3]));
            *(uint2*)(Ar + mt * 16 + q * 4) = v;
        }

        // ---- layer 2: 64 -> 32 (weights in VGPRs) ----
        v4f acc2[2];
#pragma unroll
        for (int mt = 0; mt < 2; ++mt) acc2[mt] = (v4f){0.f, 0.f, 0.f, 0.f};
#pragma unroll
        for (int ks = 0; ks < 2; ++ks) {
            v8s b = *(const v8s*)(Ar + ks * 32 + q * 8);
#pragma unroll
            for (int mt = 0; mt < 2; ++mt)
                acc2[mt] = __builtin_amdgcn_mfma_f32_16x16x32_bf16(w2f[mt][ks], b, acc2[mt], 0, 0, 0);
        }
#pragma unroll
        for (int mt = 0; mt < 2; ++mt) {
            uint2 v;
            v.x = pk2(leaky(acc2[mt][0]), leaky(acc2[mt][1]));
            v.y = pk2(leaky(acc2[mt][2]), leaky(acc2[mt][3]));
            *(uint2*)(Ar + mt * 16 + q * 4) = v;
        }

        // ---- layer 3: 32 -> 16, fused 16->8->1, fuse with weights2 ----
        {
            v8s b = *(const v8s*)(Ar + q * 8);
            v4f acc3 = __builtin_amdgcn_mfma_f32_16x16x32_bf16(w3f, b, (v4f){0.f, 0.f, 0.f, 0.f}, 0, 0, 0);

            float part = 0.f;
#pragma unroll
            for (int r = 0; r < 4; ++r) part += w45[r] * leaky(acc3[r]);
            part += __shfl_xor(part, 16, 64);
            part += __shfl_xor(part, 32, 64);

            if (q == 0) {
                out[gbase + p] = fa * part + fb * w2tab[((y & 1) << 1) | (p & 1)];
            }
        }
    }
}

extern "C" void kernel_launch(void* const* d_in, const int* in_sizes, int n_in,
                              void* d_out, int out_size, void* d_ws, size_t ws_size,
                              hipStream_t stream) {
    const float* lr  = (const float*)d_in[0];
    const float* hr  = (const float*)d_in[1];
    const float* w0g = (const float*)d_in[2];
    const float* w1g = (const float*)d_in[3];
    const float* w2g = (const float*)d_in[4];
    const float* w3g = (const float*)d_in[5];
    const float* w4g = (const float*)d_in[6];
    const float* w5g = (const float*)d_in[7];
    const float* t0g = (const float*)d_in[8];
    const float* t1g = (const float*)d_in[9];
    const float* t2g = (const float*)d_in[10];
    const float* fwg = (const float*)d_in[11];
    float* out = (float*)d_out;

    hipLaunchKernelGGL(cmfsm_kernel, dim3(NBLK), dim3(1024), LDS_BYTES, stream,
                       lr, hr, w0g, w1g, w2g, w3g, w4g, w5g, t0g, t1g, t2g, fwg, out);
}

// Round 4
// 149.519 us; speedup vs baseline: 1.1504x; 1.1504x over previous
//
#include <hip/hip_runtime.h>

typedef short v8s __attribute__((ext_vector_type(8)));
typedef float v4f __attribute__((ext_vector_type(4)));

#define Wh   1024
#define Hh   512
#define HWh  (Wh * Hh)
#define Wlr  512
#define HWlr (Wlr * 256)
#define PAD  136          // act row stride in shorts (272 B) -> 2-way max on B-frag reads
#define ITERS 8
#define NBLK  256         // 256 blocks x 16 waves x 8 iters x 16 px = 524288 px

// LDS layout (shorts):
//   wfrag[53*512]  : 53 fragments (W0:32, W1:16, W2:4, W3:1), each 64 lanes x 8 bf16,
//                    lane-contiguous -> conflict-free ds_read_b128
//   actS[16][16*PAD]: per-wave private activation buffer (16 px x 128 ch + pad)
#define WFRAG_SHORTS (53 * 512)
#define ACT_SHORTS   (16 * PAD)
#define LDS_BYTES    ((WFRAG_SHORTS + 16 * ACT_SHORTS) * 2)   // 54272 + 69632 = 123904

__device__ __forceinline__ unsigned short f2bf(float f) {
    union { float f; unsigned u; } v; v.f = f;
    unsigned r = v.u + 0x7FFFu + ((v.u >> 16) & 1u);  // RNE (cold paths only)
    return (unsigned short)(r >> 16);
}
// hot-path pack: round-half-up bias + v_perm to grab the two high halves (3 VALU)
__device__ __forceinline__ unsigned pk2(float a, float b) {
    union { float f; unsigned u; } ua, ub;
    ua.f = a; ub.f = b;
    return __builtin_amdgcn_perm(ub.u + 0x8000u, ua.u + 0x8000u, 0x07060302u);
}
__device__ __forceinline__ float leaky(float x) { return fmaxf(x, 0.01f * x); }

__global__ __launch_bounds__(1024, 4)
void cmfsm_kernel(const float* __restrict__ lr, const float* __restrict__ hr,
                  const float* __restrict__ w0g, const float* __restrict__ w1g,
                  const float* __restrict__ w2g, const float* __restrict__ w3g,
                  const float* __restrict__ w4g, const float* __restrict__ w5g,
                  const float* __restrict__ t0g, const float* __restrict__ t1g,
                  const float* __restrict__ t2g, const float* __restrict__ fwg,
                  float* __restrict__ out)
{
    extern __shared__ unsigned short smem[];
    unsigned short* wfrag = smem;                    // 53*512 shorts
    unsigned short* actS  = smem + WFRAG_SHORTS;

    const int tid  = threadIdx.x;
    const int lane = tid & 63;
    const int wv   = tid >> 6;
    const int p    = lane & 15;   // MFMA n (pixel)
    const int q    = lane >> 4;   // MFMA k-quad

    // ---- stage weights as A-fragments into LDS, fragment-major ----
    for (int e = tid; e < 32 * 64; e += 1024) {
        int f = e >> 6, l = e & 63;
        int mt = f >> 2, ks = f & 3, pp = l & 15, qq = l >> 4;
        const float* src = w0g + (mt * 16 + pp) * 128 + ks * 32 + qq * 8;
        unsigned short* dst = wfrag + f * 512 + l * 8;
#pragma unroll
        for (int j = 0; j < 8; ++j) dst[j] = f2bf(src[j]);
    }
    if (tid < 16 * 64) {
        int f = tid >> 6, l = tid & 63;
        int mt = f >> 2, ks = f & 3, pp = l & 15, qq = l >> 4;
        const float* src = w1g + (mt * 16 + pp) * 128 + ks * 32 + qq * 8;
        unsigned short* dst = wfrag + (32 + f) * 512 + l * 8;
#pragma unroll
        for (int j = 0; j < 8; ++j) dst[j] = f2bf(src[j]);
    }
    if (tid < 4 * 64) {
        int f = tid >> 6, l = tid & 63;
        int mt = f >> 1, ks = f & 1, pp = l & 15, qq = l >> 4;
        const float* src = w2g + (mt * 16 + pp) * 64 + ks * 32 + qq * 8;
        unsigned short* dst = wfrag + (48 + f) * 512 + l * 8;
#pragma unroll
        for (int j = 0; j < 8; ++j) dst[j] = f2bf(src[j]);
    }
    if (tid < 64) {
        int l = tid;
        int pp = l & 15, qq = l >> 4;
        const float* src = w3g + pp * 32 + qq * 8;
        unsigned short* dst = wfrag + 52 * 512 + l * 8;
#pragma unroll
        for (int j = 0; j < 8; ++j) dst[j] = f2bf(src[j]);
    }

    // ---- fused linear layers 4+5: w45[r] = sum_j w5[j]*w4[j][4q+r] ----
    float w45[4];
#pragma unroll
    for (int r = 0; r < 4; ++r) {
        float s = 0.f;
#pragma unroll
        for (int j = 0; j < 8; ++j) s += w5g[j] * w4g[j * 16 + q * 4 + r];
        w45[r] = s;
    }

    // ---- weights2: only 4 parity values ----
    float w2tab[4];
#pragma unroll
    for (int yp = 0; yp < 2; ++yp)
#pragma unroll
        for (int xp = 0; xp < 2; ++xp) {
            float i0 = xp ? 1.f : -1.f;
            float i1 = yp ? 1.f : -1.f;
            float i2 = 1.41421356237309505f;
            float h0[3], h1[2];
            for (int o = 0; o < 3; ++o)
                h0[o] = leaky(t0g[o*3+0]*i0 + t0g[o*3+1]*i1 + t0g[o*3+2]*i2);
            for (int o = 0; o < 2; ++o)
                h1[o] = leaky(t1g[o*3+0]*h0[0] + t1g[o*3+1]*h0[1] + t1g[o*3+2]*h0[2]);
            w2tab[yp*2+xp] = t2g[0]*h1[0] + t2g[1]*h1[1];
        }
    const float fa = fabsf(fwg[0]);
    const float fb = fabsf(fwg[1]);

    __syncthreads();   // wfrag ready; everything after is wave-private

    unsigned short* A = actS + wv * ACT_SHORTS;

    for (int it = 0; it < ITERS; ++it) {
        const int gbase = (blockIdx.x * ITERS + it) * 256 + wv * 16;  // 16 consecutive px
        const int y     = gbase >> 10;
        const int x0    = gbase & 1023;
        const int xg    = x0 + p;

        // ---- build rep[p][0..127] in LDS (bf16), 2 channels/lane/pass ----
#pragma unroll
        for (int pass = 0; pass < 4; ++pass) {
            int ch = pass * 8 + q * 2;
            const float* hp = hr + (size_t)ch * HWh + (size_t)y * Wh + xg;
            float h0 = hp[0];
            float h1 = hp[HWh];
            const float* lp = lr + (size_t)ch * HWlr + (size_t)(y >> 1) * Wlr + (xg >> 1);
            float l0 = lp[0];
            float l1 = lp[HWlr];
            unsigned* Ap = (unsigned*)(A + p * PAD);
            Ap[ch >> 1]        = pk2(l0, l1);            // lr_up
            Ap[(32 + ch) >> 1] = pk2(h0, h1);            // hr
            Ap[(64 + ch) >> 1] = pk2(l0 * h0, l1 * h1);  // product
            float d0 = l0 - h0, d1 = l1 - h1;
            Ap[(96 + ch) >> 1] = pk2(d0 * d0, d1 * d1);  // squared diff
        }

        // ---- layer 0: 128 -> 128 ----
        v4f acc0[8];
#pragma unroll
        for (int mt = 0; mt < 8; ++mt) acc0[mt] = (v4f){0.f, 0.f, 0.f, 0.f};
#pragma unroll
        for (int ks = 0; ks < 4; ++ks) {
            v8s b = *(const v8s*)(A + p * PAD + ks * 32 + q * 8);
#pragma unroll
            for (int mt = 0; mt < 8; ++mt) {
                v8s a = *(const v8s*)(wfrag + (mt * 4 + ks) * 512 + lane * 8);
                acc0[mt] = __builtin_amdgcn_mfma_f32_16x16x32_bf16(a, b, acc0[mt], 0, 0, 0);
            }
        }
#pragma unroll
        for (int mt = 0; mt < 8; ++mt) {
            uint2 v;
            v.x = pk2(leaky(acc0[mt][0]), leaky(acc0[mt][1]));
            v.y = pk2(leaky(acc0[mt][2]), leaky(acc0[mt][3]));
            *(uint2*)(A + p * PAD + mt * 16 + q * 4) = v;   // act[p][16mt+4q+r]
        }

        // ---- layer 1: 128 -> 64 ----
        v4f acc1[4];
#pragma unroll
        for (int mt = 0; mt < 4; ++mt) acc1[mt] = (v4f){0.f, 0.f, 0.f, 0.f};
#pragma unroll
        for (int ks = 0; ks < 4; ++ks) {
            v8s b = *(const v8s*)(A + p * PAD + ks * 32 + q * 8);
#pragma unroll
            for (int mt = 0; mt < 4; ++mt) {
                v8s a = *(const v8s*)(wfrag + (32 + mt * 4 + ks) * 512 + lane * 8);
                acc1[mt] = __builtin_amdgcn_mfma_f32_16x16x32_bf16(a, b, acc1[mt], 0, 0, 0);
            }
        }
#pragma unroll
        for (int mt = 0; mt < 4; ++mt) {
            uint2 v;
            v.x = pk2(leaky(acc1[mt][0]), leaky(acc1[mt][1]));
            v.y = pk2(leaky(acc1[mt][2]), leaky(acc1[mt][3]));
            *(uint2*)(A + p * PAD + mt * 16 + q * 4) = v;
        }

        // ---- layer 2: 64 -> 32 ----
        v4f acc2[2];
#pragma unroll
        for (int mt = 0; mt < 2; ++mt) acc2[mt] = (v4f){0.f, 0.f, 0.f, 0.f};
#pragma unroll
        for (int ks = 0; ks < 2; ++ks) {
            v8s b = *(const v8s*)(A + p * PAD + ks * 32 + q * 8);
#pragma unroll
            for (int mt = 0; mt < 2; ++mt) {
                v8s a = *(const v8s*)(wfrag + (48 + mt * 2 + ks) * 512 + lane * 8);
                acc2[mt] = __builtin_amdgcn_mfma_f32_16x16x32_bf16(a, b, acc2[mt], 0, 0, 0);
            }
        }
#pragma unroll
        for (int mt = 0; mt < 2; ++mt) {
            uint2 v;
            v.x = pk2(leaky(acc2[mt][0]), leaky(acc2[mt][1]));
            v.y = pk2(leaky(acc2[mt][2]), leaky(acc2[mt][3]));
            *(uint2*)(A + p * PAD + mt * 16 + q * 4) = v;
        }

        // ---- layer 3: 32 -> 16, fused 16->8->1, fuse with weights2 ----
        {
            v8s b = *(const v8s*)(A + p * PAD + q * 8);
            v8s a = *(const v8s*)(wfrag + 52 * 512 + lane * 8);
            v4f acc3 = __builtin_amdgcn_mfma_f32_16x16x32_bf16(a, b, (v4f){0.f, 0.f, 0.f, 0.f}, 0, 0, 0);

            float part = 0.f;
#pragma unroll
            for (int r = 0; r < 4; ++r) part += w45[r] * leaky(acc3[r]);
            part += __shfl_xor(part, 16, 64);
            part += __shfl_xor(part, 32, 64);

            if (q == 0) {
                float res = fa * part + fb * w2tab[(y & 1) * 2 + (xg & 1)];
                out[y * Wh + xg] = res;
            }
        }
    }
}

extern "C" void kernel_launch(void* const* d_in, const int* in_sizes, int n_in,
                              void* d_out, int out_size, void* d_ws, size_t ws_size,
                              hipStream_t stream) {
    const float* lr  = (const float*)d_in[0];
    const float* hr  = (const float*)d_in[1];
    const float* w0g = (const float*)d_in[2];
    const float* w1g = (const float*)d_in[3];
    const float* w2g = (const float*)d_in[4];
    const float* w3g = (const float*)d_in[5];
    const float* w4g = (const float*)d_in[6];
    const float* w5g = (const float*)d_in[7];
    const float* t0g = (const float*)d_in[8];
    const float* t1g = (const float*)d_in[9];
    const float* t2g = (const float*)d_in[10];
    const float* fwg = (const float*)d_in[11];
    float* out = (float*)d_out;

    hipLaunchKernelGGL(cmfsm_kernel, dim3(NBLK), dim3(1024), LDS_BYTES, stream,
                       lr, hr, w0g, w1g, w2g, w3g, w4g, w5g, t0g, t1g, t2g, fwg, out);
}